// Round 10
// baseline (310.937 us; speedup 1.0000x reference)
//
#include <hip/hip_runtime.h>
#include <hip/hip_bf16.h>
#include <stdint.h>

// ---- types ----
typedef float   floatx4  __attribute__((ext_vector_type(4)));
typedef int     intx4    __attribute__((ext_vector_type(4)));
typedef int     intx8    __attribute__((ext_vector_type(8)));
typedef _Float16 halfx8  __attribute__((ext_vector_type(8)));
typedef _Float16 halfx4  __attribute__((ext_vector_type(4)));

#define NROW 8192
#define NDIM 2048        // elements = bytes (fp8)
#define BM 128
#define BKB 128          // bytes per row per K-stage = 128 fp8 = 8 x 16B chunks
#define NSTRIP 64                       // NROW/BM
#define NOFF (NSTRIP*(NSTRIP-1)/2)      // 2016 off-diagonal tiles (dispatched first)
#define NTILE (NSTRIP*(NSTRIP+1)/2)     // 2080 total tiles
#define DT_LD 136        // Dt row stride in halves (272 B; rows 16B-aligned)
#define KL_SYM 64        // one 5-list per row per other-strip

// insert v into descending-sorted a[5] (keeps 5 largest)
__device__ __forceinline__ void ins_desc(float (&a)[5], float v) {
#pragma unroll
    for (int k = 0; k < 5; ++k) { float hi = fmaxf(a[k], v); float lo = fminf(a[k], v); a[k] = hi; v = lo; }
}
// insert v into ascending-sorted a[5] (keeps 5 smallest)
__device__ __forceinline__ void ins_asc(float (&a)[5], float v) {
#pragma unroll
    for (int k = 0; k < 5; ++k) { float lo = fminf(a[k], v); float hi = fmaxf(a[k], v); a[k] = lo; v = hi; }
}

__device__ __forceinline__ void load_lds16(const void* g, void* l) {
    // async global->LDS, 16B/lane, dest = wave-uniform base + lane*16
    __builtin_amdgcn_global_load_lds((__attribute__((address_space(1))) void*)(void*)g,
                                     (__attribute__((address_space(3))) void*)l,
                                     16, 0, 0);
}

// ---- kernel 1: L2 normalize rows, write fp8-e4m3 matrix + sq ----
// fp8 verified numerically in R8/R9 (absmax 0.0078 == bf16 path).
__global__ __launch_bounds__(256) void k_normalize(const float* __restrict__ feats,
                                                   unsigned char* __restrict__ xb,
                                                   float* __restrict__ sq) {
    const int row = blockIdx.x;
    const int t = threadIdx.x;
    const float* f = feats + (size_t)row * NDIM + t * 8;
    float4 v0 = *(const float4*)(f);
    float4 v1 = *(const float4*)(f + 4);
    float ss = v0.x*v0.x + v0.y*v0.y + v0.z*v0.z + v0.w*v0.w
             + v1.x*v1.x + v1.y*v1.y + v1.z*v1.z + v1.w*v1.w;
#pragma unroll
    for (int o = 32; o > 0; o >>= 1) ss += __shfl_down(ss, o);
    __shared__ float red[4];
    __shared__ float s_inv;
    if ((t & 63) == 0) red[t >> 6] = ss;
    __syncthreads();
    if (t == 0) {
        float tot = red[0] + red[1] + red[2] + red[3];
        float m = fmaxf(sqrtf(tot), 1e-12f);
        float inv = 1.0f / m;
        sq[row] = tot * inv * inv;
        s_inv = inv;
    }
    __syncthreads();
    float inv = s_inv;
    // pack 8 normalized floats -> 8 fp8 e4m3 (HW cvt)
    int w0 = __builtin_amdgcn_cvt_pk_fp8_f32(v0.x * inv, v0.y * inv, 0, false);
    w0     = __builtin_amdgcn_cvt_pk_fp8_f32(v0.z * inv, v0.w * inv, w0, true);
    int w1 = __builtin_amdgcn_cvt_pk_fp8_f32(v1.x * inv, v1.y * inv, 0, false);
    w1     = __builtin_amdgcn_cvt_pk_fp8_f32(v1.z * inv, v1.w * inv, w1, true);
    int2 pk; pk.x = w0; pk.y = w1;
    *(int2*)(xb + (size_t)row * NDIM + t * 8) = pk;
}

// ---- scan helper (R5-exact): half-row scan over 64 cols in d2 domain ----
__device__ __forceinline__ void scan_half_row(const _Float16* Dt_, const int* labcam_cols,
        int srow, int shalf, int pli, float (&pos5)[5], float (&neg5)[5]) {
    const int jb = shalf * 64;
    const int sw = srow & 7;
#pragma unroll
    for (int c8 = 0; c8 < 8; ++c8) {
        // physical chunk = logical chunk ^ (row&7); labels indexed logically
        halfx8 v = *(const halfx8*)(Dt_ + srow * DT_LD + ((shalf * 8 + (c8 ^ sw)) << 3));
        int4 lc0 = *(const int4*)(labcam_cols + jb + c8 * 8);
        int4 lc1 = *(const int4*)(labcam_cols + jb + c8 * 8 + 4);
        int lcv[8] = {lc0.x, lc0.y, lc0.z, lc0.w, lc1.x, lc1.y, lc1.z, lc1.w};
#pragma unroll
        for (int e = 0; e < 8; ++e) {
            float d2 = (float)v[e];
            int x = pli ^ lcv[e];
            bool same_label = (x & ~15) == 0;
            bool same_cam   = (x & 15) == 0;
            if (same_label) {
                // positive: same label, cross-cam (i==j auto-excluded: same cam)
                if (!same_cam && d2 > pos5[4]) ins_desc(pos5, d2);
            } else {
                // negative: diff label; same-cam boost dist/1.2 == d2/1.44 (monotone)
                float vn = same_cam ? d2 * (1.0f / 1.44f) : d2;
                if (vn < neg5[4]) ins_asc(neg5, vn);
            }
        }
    }
}

// merge the two half-row lists (adjacent lanes; snapshot-then-insert) and emit fp16
__device__ __forceinline__ void emit_lists(float (&pos5)[5], float (&neg5)[5], int shalf,
        _Float16* posp, _Float16* negp, size_t gi, int slot) {
    float tp[5], tn[5];
#pragma unroll
    for (int k = 0; k < 5; ++k) { tp[k] = __shfl_xor(pos5[k], 1); tn[k] = __shfl_xor(neg5[k], 1); }
#pragma unroll
    for (int k = 0; k < 5; ++k) {
        if (tp[k] > pos5[4]) ins_desc(pos5, tp[k]);
        if (tn[k] < neg5[4]) ins_asc(neg5, tn[k]);
    }
    if (shalf == 0) {
        _Float16* pp = posp + (gi * KL_SYM + slot) * 5;
        _Float16* np = negp + (gi * KL_SYM + slot) * 5;
#pragma unroll
        for (int k = 0; k < 5; ++k) { pp[k] = (_Float16)pos5[k]; np[k] = (_Float16)neg5[k]; }
    }
}

// ---- kernel 2 (sym): one block per triangle tile (a,b), b<=a; diagonals last.
// MX-fp8 K-loop (layout verified R8/R9).  __launch_bounds__(256,4): R9's
// shufflevector fragments compile to VGPR_Count=84 <= the 128 cap, so the 4th
// block/CU is free (R8's 476 MB spill was the union-based code at this cap —
// watch WRITE_SIZE ~61 MB as the no-spill signature).
__global__ __launch_bounds__(256, 4) void k_gemm_sym(
        const unsigned char* __restrict__ xb, const float* __restrict__ sq,
        const int* __restrict__ labels, const int* __restrict__ camids,
        _Float16* __restrict__ posp, _Float16* __restrict__ negp) {
    __shared__ __align__(16) char smem[BM * DT_LD * 2 + 4 * BM * 4];
    char* As = smem;                          // [0, 16384)
    char* Bs = smem + BM * BKB;               // [16384, 32768)
    _Float16* Dt = (_Float16*)smem;           // [0, 34816) aliases As/Bs
    float* sqr_s = (float*)(smem + BM * DT_LD * 2);
    float* sqc_s = sqr_s + BM;
    int* labcam_a = (int*)(sqc_s + BM);
    int* labcam_b = labcam_a + BM;

    const int tid = threadIdx.x;
    const int w = tid >> 6, lane = tid & 63;
    const int wm = w >> 1, wn = w & 1;

    // tile decode: off-diagonal pairs (b<a) first, diagonals last (cheap tail)
    int a, b;
    {
        int bx = blockIdx.x;
        if (bx < NOFF) {
            a = (int)((1.0f + sqrtf(8.0f * (float)bx + 1.0f)) * 0.5f);
            while (a * (a - 1) / 2 > bx) --a;
            while (a * (a + 1) / 2 <= bx) ++a;
            b = bx - a * (a - 1) / 2;
        } else {
            a = b = bx - NOFF;
        }
    }
    const int r0 = a * BM, c0 = b * BM;

    if (tid < BM) {
        int gi = r0 + tid;
        sqr_s[tid] = sq[gi];
        labcam_a[tid] = (labels[gi] << 4) | camids[gi];
    } else {
        int t2 = tid - BM;
        int gj = c0 + t2;
        sqc_s[t2] = sq[gj];
        labcam_b[t2] = (labels[gj] << 4) | camids[gj];
    }
    __syncthreads();

    const int srow = tid >> 1;       // scan: 2 threads per row
    const int shalf = tid & 1;

    const int lr = lane >> 3;                  // staging: row within 8-row chunk
    const int lc = ((lane & 7) ^ lr) * 16;     // staging: swizzled source chunk, bytes
    const int m16 = lane & 15;
    const int quad = lane >> 4;
    const int s7 = m16 & 7;                    // frag-read swizzle key (= row&7)
    const int pc0 = ((2 * quad) ^ s7) * 16;    // physical byte offset of logical chunk 2q
    const int pc1 = ((2 * quad + 1) ^ s7) * 16;

    floatx4 acc[4][4];
#pragma unroll
    for (int mi = 0; mi < 4; ++mi)
#pragma unroll
        for (int ni = 0; ni < 4; ++ni) {
            floatx4 z = {0.f, 0.f, 0.f, 0.f};
            acc[mi][ni] = z;
        }

    for (int kk = 0; kk < NDIM; kk += BKB) {   // 16 stages
        __syncthreads();             // previous iter's LDS consumers done
#pragma unroll
        for (int q = 0; q < 4; ++q) {
            const int ra = w * 32 + q * 8;    // wave-uniform 8-row chunk base
            load_lds16(xb + (size_t)(r0 + ra + lr) * NDIM + kk + lc, As + ra * BKB);
            load_lds16(xb + (size_t)(c0 + ra + lr) * NDIM + kk + lc, Bs + ra * BKB);
        }
        __syncthreads();             // drains vmcnt(0): data in LDS
        intx8 bfr[4];
#pragma unroll
        for (int ni = 0; ni < 4; ++ni) {
            const char* bp = Bs + (wn * 64 + ni * 16 + m16) * BKB;
            intx4 lo = *(const intx4*)(bp + pc0);
            intx4 hi = *(const intx4*)(bp + pc1);
            bfr[ni] = __builtin_shufflevector(lo, hi, 0, 1, 2, 3, 4, 5, 6, 7);
        }
#pragma unroll
        for (int mi = 0; mi < 4; ++mi) {
            const char* ap = As + (wm * 64 + mi * 16 + m16) * BKB;
            intx4 lo = *(const intx4*)(ap + pc0);
            intx4 hi = *(const intx4*)(ap + pc1);
            intx8 af = __builtin_shufflevector(lo, hi, 0, 1, 2, 3, 4, 5, 6, 7);
#pragma unroll
            for (int ni = 0; ni < 4; ++ni)
                acc[mi][ni] = __builtin_amdgcn_mfma_scale_f32_16x16x128_f8f6f4(
                    af, bfr[ni], acc[mi][ni], 0, 0, 0, 127, 0, 127);
        }
    }
    __syncthreads();                 // all ds_reads of As/Bs done before Dt overwrite

    // ---- pass 1: d2 row-major (chunk-swizzled); scan rows of strip a ----
    // 16x16 C layout: col = lane&15, row = quad*4 + reg
#pragma unroll
    for (int mi = 0; mi < 4; ++mi) {
        const int il = wm * 64 + mi * 16 + quad * 4;
#pragma unroll
        for (int ni = 0; ni < 4; ++ni) {
            const int jl = wn * 64 + ni * 16 + m16;
            const float sj = sqc_s[jl];
#pragma unroll
            for (int r = 0; r < 4; ++r) {
                float d2 = fmaxf(sqr_s[il + r] + sj - 2.0f * acc[mi][ni][r], 1e-12f);
                const int rw7 = (il + r) & 7;
                Dt[(il + r) * DT_LD + ((((jl >> 3) ^ rw7) << 3) | (jl & 7))] = (_Float16)d2;
            }
        }
    }
    __syncthreads();

    const float NINF = -__builtin_inff();
    const float PINF =  __builtin_inff();
    float pos5[5] = {NINF, NINF, NINF, NINF, NINF};
    float neg5[5] = {PINF, PINF, PINF, PINF, PINF};
    scan_half_row(Dt, labcam_b, srow, shalf, labcam_a[srow], pos5, neg5);
    emit_lists(pos5, neg5, shalf, posp, negp, (size_t)(r0 + srow), b);

    if (a != b) {
        __syncthreads();             // pass-1 scan reads done before Dt overwrite
        // ---- pass 2: d2 transposed (b64 packed, swizzled); scan rows of strip b ----
#pragma unroll
        for (int ni = 0; ni < 4; ++ni) {
            const int jl = wn * 64 + ni * 16 + m16;
            const float sj = sqc_s[jl];
            const int cw = jl & 7;
#pragma unroll
            for (int mi = 0; mi < 4; ++mi) {
                const int il = wm * 64 + mi * 16 + quad * 4;
                halfx4 h;
#pragma unroll
                for (int r = 0; r < 4; ++r)
                    h[r] = (_Float16)fmaxf(sqr_s[il + r] + sj - 2.0f * acc[mi][ni][r], 1e-12f);
                *(halfx4*)(Dt + jl * DT_LD + ((((il >> 3) ^ cw) << 3) | (il & 7))) = h;
            }
        }
        __syncthreads();
#pragma unroll
        for (int k = 0; k < 5; ++k) { pos5[k] = NINF; neg5[k] = PINF; }
        scan_half_row(Dt, labcam_a, srow, shalf, labcam_b[srow], pos5, neg5);
        emit_lists(pos5, neg5, shalf, posp, negp, (size_t)(c0 + srow), a);
    }
}

// ---- kernel 3 (R5-exact): merge 64 fp16 d2-lists/row, 4 thr/row, 1024-thr blocks ----
__global__ __launch_bounds__(1024) void k_merge_sym(const _Float16* __restrict__ posp,
        const _Float16* __restrict__ negp, const int* __restrict__ epoch_p,
        float* __restrict__ out, float* __restrict__ wsum_p, float* __restrict__ wpsum_p) {
    const int t = threadIdx.x;
    const int rq = t & 3;                       // quarter of the row's 320 halves
    const int row = blockIdx.x * 256 + (t >> 2);
    const float NINF = -__builtin_inff(), PINF = __builtin_inff();
    float p5[5] = {NINF, NINF, NINF, NINF, NINF};
    float n5[5] = {PINF, PINF, PINF, PINF, PINF};
    const halfx8* pv8 = (const halfx8*)(posp + (size_t)row * (KL_SYM * 5) + rq * 80);
    const halfx8* nv8 = (const halfx8*)(negp + (size_t)row * (KL_SYM * 5) + rq * 80);
#pragma unroll
    for (int k = 0; k < 10; ++k) {
        halfx8 v = pv8[k];
#pragma unroll
        for (int e = 0; e < 8; ++e) { float f = (float)v[e]; if (f > p5[4]) ins_desc(p5, f); }
    }
#pragma unroll
    for (int k = 0; k < 10; ++k) {
        halfx8 v = nv8[k];
#pragma unroll
        for (int e = 0; e < 8; ++e) { float f = (float)v[e]; if (f < n5[4]) ins_asc(n5, f); }
    }
    // butterfly merge across the 4 lanes of this row (snapshot-then-insert)
#pragma unroll
    for (int o = 1; o <= 2; o <<= 1) {
        float tp[5], tn[5];
#pragma unroll
        for (int k = 0; k < 5; ++k) { tp[k] = __shfl_xor(p5[k], o); tn[k] = __shfl_xor(n5[k], o); }
#pragma unroll
        for (int k = 0; k < 5; ++k) {
            if (tp[k] > p5[4]) ins_desc(p5, tp[k]);
            if (tn[k] < n5[4]) ins_asc(n5, tn[k]);
        }
    }
    // d2 -> dist on the 5 survivors only
    float s = 0.f; int c = 0;
#pragma unroll
    for (int k = 0; k < 5; ++k) { bool fin = (p5[k] > NINF); s += fin ? sqrtf(p5[k]) : 0.f; c += fin ? 1 : 0; }
    float d_ap = (c > 0) ? s / (float)c : NINF;
    s = 0.f; c = 0;
#pragma unroll
    for (int k = 0; k < 5; ++k) { bool fin = (n5[k] < PINF); s += fin ? sqrtf(n5[k]) : 0.f; c += fin ? 1 : 0; }
    float d_an = (c > 0) ? s / (float)c : PINF;

    float w0 = 0.f, wp = 0.f;
    if (rq == 0) {
        out[1 + row] = d_ap;
        out[1 + NROW + row] = d_an;
        float diff = d_ap - d_an;
        w0 = 1.0f / (1.0f + expf(-2.0f * diff));         // sigmoid(ALPHA*(d_ap-d_an))
        float p;
        if (*epoch_p < 10) {
            p = fmaxf(diff, 0.0f) + log1pf(expf(-fabsf(diff)));  // stable softplus
        } else {
            p = fmaxf(diff + 0.3f, 0.0f);                // relu(d_ap - d_an + MARGIN)
        }
        wp = w0 * p;
    }
#pragma unroll
    for (int o = 32; o > 0; o >>= 1) { w0 += __shfl_down(w0, o); wp += __shfl_down(wp, o); }
    __shared__ float rw[16], rp[16];
    if ((t & 63) == 0) { rw[t >> 6] = w0; rp[t >> 6] = wp; }
    __syncthreads();
    if (t == 0) {
        float sw = 0.f, swp = 0.f;
#pragma unroll
        for (int i = 0; i < 16; ++i) { sw += rw[i]; swp += rp[i]; }
        wsum_p[blockIdx.x]  = sw;
        wpsum_p[blockIdx.x] = swp;
    }
}

// ---- kernel 4: finalize loss scalar ----
__global__ void k_finalize(const float* __restrict__ wsum_p, const float* __restrict__ wpsum_p,
                           float* __restrict__ out) {
    if (threadIdx.x == 0) {
        float sw = 0.f, swp = 0.f;
        for (int i = 0; i < 32; ++i) { sw += wsum_p[i]; swp += wpsum_p[i]; }
        float M = fmaxf(sw / (float)NROW, 1e-12f);
        out[0] = swp / ((float)NROW * M);
    }
}

extern "C" void kernel_launch(void* const* d_in, const int* in_sizes, int n_in,
                              void* d_out, int out_size, void* d_ws, size_t ws_size,
                              hipStream_t stream) {
    const float* feats  = (const float*)d_in[0];
    const int*   labels = (const int*)d_in[1];
    const int*   camids = (const int*)d_in[2];
    const int*   epoch  = (const int*)d_in[3];
    float* out = (float*)d_out;
    char* ws = (char*)d_ws;

    // workspace layout (~27.3 MB; ws proven >= 44 MB in R4-R9)
    unsigned char* xb = (unsigned char*)ws;                            // 16,777,216 B
    float* sq = (float*)(ws + 16777216);                               //     32,768 B
    const size_t HALF_LIST_BYTES = (size_t)NROW * KL_SYM * 5 * 2;      //  5,242,880 B
    _Float16* posp = (_Float16*)(ws + 16777216 + 32768);
    _Float16* negp = (_Float16*)(ws + 16777216 + 32768 + HALF_LIST_BYTES);
    float* wsum_p  = (float*)(ws + 16777216 + 32768 + 2 * HALF_LIST_BYTES);
    float* wpsum_p = wsum_p + 32;

    k_normalize<<<NROW, 256, 0, stream>>>(feats, xb, sq);
    k_gemm_sym<<<NTILE, 256, 0, stream>>>(xb, sq, labels, camids, posp, negp);
    k_merge_sym<<<NROW / 256, 1024, 0, stream>>>(posp, negp, epoch, out, wsum_p, wpsum_p);
    k_finalize<<<1, 64, 0, stream>>>(wsum_p, wpsum_p, out);
}

// Round 11
// 284.108 us; speedup vs baseline: 1.0944x; 1.0944x over previous
//
#include <hip/hip_runtime.h>
#include <hip/hip_bf16.h>
#include <stdint.h>

// ---- types ----
typedef float   floatx4  __attribute__((ext_vector_type(4)));
typedef int     intx4    __attribute__((ext_vector_type(4)));
typedef int     intx8    __attribute__((ext_vector_type(8)));
typedef _Float16 halfx8  __attribute__((ext_vector_type(8)));
typedef _Float16 halfx4  __attribute__((ext_vector_type(4)));

#define NROW 8192
#define NDIM 2048        // elements = bytes (fp8)
#define BM 128
#define BKB 128          // bytes per row per K-stage = 128 fp8 = 8 x 16B chunks
#define NSTRIP 64                       // NROW/BM
#define NOFF (NSTRIP*(NSTRIP-1)/2)      // 2016 off-diagonal tiles (dispatched first)
#define NTILE (NSTRIP*(NSTRIP+1)/2)     // 2080 total tiles
#define DT_LD 136        // Dt row stride in halves (272 B; rows 16B-aligned)
#define KL_SYM 64        // one 5-list per row per other-strip

// insert v into descending-sorted a[5] (keeps 5 largest)
__device__ __forceinline__ void ins_desc(float (&a)[5], float v) {
#pragma unroll
    for (int k = 0; k < 5; ++k) { float hi = fmaxf(a[k], v); float lo = fminf(a[k], v); a[k] = hi; v = lo; }
}
// insert v into ascending-sorted a[5] (keeps 5 smallest)
__device__ __forceinline__ void ins_asc(float (&a)[5], float v) {
#pragma unroll
    for (int k = 0; k < 5; ++k) { float lo = fminf(a[k], v); float hi = fmaxf(a[k], v); a[k] = lo; v = hi; }
}

__device__ __forceinline__ void load_lds16(const void* g, void* l) {
    // async global->LDS, 16B/lane, dest = wave-uniform base + lane*16
    __builtin_amdgcn_global_load_lds((__attribute__((address_space(1))) void*)(void*)g,
                                     (__attribute__((address_space(3))) void*)l,
                                     16, 0, 0);
}

// ---- kernel 1: L2 normalize rows, write fp8-e4m3 matrix + sq ----
// fp8 verified numerically in R8/R9 (absmax 0.0078 == bf16 path).
__global__ __launch_bounds__(256) void k_normalize(const float* __restrict__ feats,
                                                   unsigned char* __restrict__ xb,
                                                   float* __restrict__ sq) {
    const int row = blockIdx.x;
    const int t = threadIdx.x;
    const float* f = feats + (size_t)row * NDIM + t * 8;
    float4 v0 = *(const float4*)(f);
    float4 v1 = *(const float4*)(f + 4);
    float ss = v0.x*v0.x + v0.y*v0.y + v0.z*v0.z + v0.w*v0.w
             + v1.x*v1.x + v1.y*v1.y + v1.z*v1.z + v1.w*v1.w;
#pragma unroll
    for (int o = 32; o > 0; o >>= 1) ss += __shfl_down(ss, o);
    __shared__ float red[4];
    __shared__ float s_inv;
    if ((t & 63) == 0) red[t >> 6] = ss;
    __syncthreads();
    if (t == 0) {
        float tot = red[0] + red[1] + red[2] + red[3];
        float m = fmaxf(sqrtf(tot), 1e-12f);
        float inv = 1.0f / m;
        sq[row] = tot * inv * inv;
        s_inv = inv;
    }
    __syncthreads();
    float inv = s_inv;
    // pack 8 normalized floats -> 8 fp8 e4m3 (HW cvt)
    int w0 = __builtin_amdgcn_cvt_pk_fp8_f32(v0.x * inv, v0.y * inv, 0, false);
    w0     = __builtin_amdgcn_cvt_pk_fp8_f32(v0.z * inv, v0.w * inv, w0, true);
    int w1 = __builtin_amdgcn_cvt_pk_fp8_f32(v1.x * inv, v1.y * inv, 0, false);
    w1     = __builtin_amdgcn_cvt_pk_fp8_f32(v1.z * inv, v1.w * inv, w1, true);
    int2 pk; pk.x = w0; pk.y = w1;
    *(int2*)(xb + (size_t)row * NDIM + t * 8) = pk;
}

// ---- scan helper: quarter-row scan over 32 cols in d2 domain (Dt chunk-swizzled).
// Physical chunk of logical chunk L (0..15) in row r: (L&8) | ((L&7) ^ (r&7)) —
// same bijection as R5/R9, generalized from half-row to quarter-row callers.
__device__ __forceinline__ void scan_quarter_row(const _Float16* Dt_, const int* labcam_cols,
        int srow, int squad, int pli, float (&pos5)[5], float (&neg5)[5]) {
    const int jb = squad * 32;
    const int sw = srow & 7;
#pragma unroll
    for (int c = 0; c < 4; ++c) {
        const int L = squad * 4 + c;                  // logical chunk 0..15
        const int P = (L & 8) | ((L & 7) ^ sw);       // physical chunk
        halfx8 v = *(const halfx8*)(Dt_ + srow * DT_LD + (P << 3));
        int4 lc0 = *(const int4*)(labcam_cols + jb + c * 8);
        int4 lc1 = *(const int4*)(labcam_cols + jb + c * 8 + 4);
        int lcv[8] = {lc0.x, lc0.y, lc0.z, lc0.w, lc1.x, lc1.y, lc1.z, lc1.w};
#pragma unroll
        for (int e = 0; e < 8; ++e) {
            float d2 = (float)v[e];
            int x = pli ^ lcv[e];
            bool same_label = (x & ~15) == 0;
            bool same_cam   = (x & 15) == 0;
            if (same_label) {
                // positive: same label, cross-cam (i==j auto-excluded: same cam)
                if (!same_cam && d2 > pos5[4]) ins_desc(pos5, d2);
            } else {
                // negative: diff label; same-cam boost dist/1.2 == d2/1.44 (monotone)
                float vn = same_cam ? d2 * (1.0f / 1.44f) : d2;
                if (vn < neg5[4]) ins_asc(neg5, vn);
            }
        }
    }
}

// merge the four quarter-row lists (lane group of 4; snapshot-then-insert) and emit fp16
__device__ __forceinline__ void emit_lists4(float (&pos5)[5], float (&neg5)[5], int squad,
        _Float16* posp, _Float16* negp, size_t gi, int slot) {
#pragma unroll
    for (int o = 1; o <= 2; o <<= 1) {
        float tp[5], tn[5];
#pragma unroll
        for (int k = 0; k < 5; ++k) { tp[k] = __shfl_xor(pos5[k], o); tn[k] = __shfl_xor(neg5[k], o); }
#pragma unroll
        for (int k = 0; k < 5; ++k) {
            if (tp[k] > pos5[4]) ins_desc(pos5, tp[k]);
            if (tn[k] < neg5[4]) ins_asc(neg5, tn[k]);
        }
    }
    if (squad == 0) {
        _Float16* pp = posp + (gi * KL_SYM + slot) * 5;
        _Float16* np = negp + (gi * KL_SYM + slot) * 5;
#pragma unroll
        for (int k = 0; k < 5; ++k) { pp[k] = (_Float16)pos5[k]; np[k] = (_Float16)neg5[k]; }
    }
}

// ---- kernel 2 (sym): one block per triangle tile (a,b), b<=a; diagonals last.
// MX-fp8 K-loop (layout verified R8/R9).  512-thread blocks: 8 waves per
// 128x128 tile, each wave 32x64 -> acc = 32 regs (not 64).  R10 lesson: the
// unified VGPR/AGPR file makes acc count against the cap, so 4x256-thread
// blocks (cap 128) with a 64-reg acc spills; this shape fits cap 128 with
// ~100 live (acc32 + bfrag32 + afrag8 + addr) -> 2 blocks/CU = 16 waves/CU
// (vs R9's 12) with zero spill.  Per-lane staging/swizzle unchanged from R9.
__global__ __launch_bounds__(512, 4) void k_gemm_sym(
        const unsigned char* __restrict__ xb, const float* __restrict__ sq,
        const int* __restrict__ labels, const int* __restrict__ camids,
        _Float16* __restrict__ posp, _Float16* __restrict__ negp) {
    __shared__ __align__(16) char smem[BM * DT_LD * 2 + 4 * BM * 4];
    char* As = smem;                          // [0, 16384)
    char* Bs = smem + BM * BKB;               // [16384, 32768)
    _Float16* Dt = (_Float16*)smem;           // [0, 34816) aliases As/Bs
    float* sqr_s = (float*)(smem + BM * DT_LD * 2);
    float* sqc_s = sqr_s + BM;
    int* labcam_a = (int*)(sqc_s + BM);
    int* labcam_b = labcam_a + BM;

    const int tid = threadIdx.x;
    const int w = tid >> 6, lane = tid & 63;
    const int wm = w >> 1, wn = w & 1;        // wm: 32-row band (0..3), wn: 64-col band (0..1)

    // tile decode: off-diagonal pairs (b<a) first, diagonals last (cheap tail)
    int a, b;
    {
        int bx = blockIdx.x;
        if (bx < NOFF) {
            a = (int)((1.0f + sqrtf(8.0f * (float)bx + 1.0f)) * 0.5f);
            while (a * (a - 1) / 2 > bx) --a;
            while (a * (a + 1) / 2 <= bx) ++a;
            b = bx - a * (a - 1) / 2;
        } else {
            a = b = bx - NOFF;
        }
    }
    const int r0 = a * BM, c0 = b * BM;

    if (tid < BM) {
        int gi = r0 + tid;
        sqr_s[tid] = sq[gi];
        labcam_a[tid] = (labels[gi] << 4) | camids[gi];
    } else if (tid < 2 * BM) {
        int t2 = tid - BM;
        int gj = c0 + t2;
        sqc_s[t2] = sq[gj];
        labcam_b[t2] = (labels[gj] << 4) | camids[gj];
    }
    __syncthreads();

    const int srow = tid >> 2;       // scan: 4 threads per row
    const int squad = tid & 3;

    const int lr = lane >> 3;                  // staging: row within 8-row chunk
    const int lc = ((lane & 7) ^ lr) * 16;     // staging: swizzled source chunk, bytes
    const int m16 = lane & 15;
    const int quad = lane >> 4;
    const int s7 = m16 & 7;                    // frag-read swizzle key (= row&7)
    const int pc0 = ((2 * quad) ^ s7) * 16;    // physical byte offset of logical chunk 2q
    const int pc1 = ((2 * quad + 1) ^ s7) * 16;

    floatx4 acc[2][4];
#pragma unroll
    for (int mi = 0; mi < 2; ++mi)
#pragma unroll
        for (int ni = 0; ni < 4; ++ni) {
            floatx4 z = {0.f, 0.f, 0.f, 0.f};
            acc[mi][ni] = z;
        }

    for (int kk = 0; kk < NDIM; kk += BKB) {   // 16 stages
        __syncthreads();             // previous iter's LDS consumers done
#pragma unroll
        for (int q = 0; q < 2; ++q) {
            const int ra = w * 16 + q * 8;    // wave-uniform 8-row chunk base (8 waves x 16 rows)
            load_lds16(xb + (size_t)(r0 + ra + lr) * NDIM + kk + lc, As + ra * BKB);
            load_lds16(xb + (size_t)(c0 + ra + lr) * NDIM + kk + lc, Bs + ra * BKB);
        }
        __syncthreads();             // drains vmcnt(0): data in LDS
        intx8 bfr[4];
#pragma unroll
        for (int ni = 0; ni < 4; ++ni) {
            const char* bp = Bs + (wn * 64 + ni * 16 + m16) * BKB;
            intx4 lo = *(const intx4*)(bp + pc0);
            intx4 hi = *(const intx4*)(bp + pc1);
            bfr[ni] = __builtin_shufflevector(lo, hi, 0, 1, 2, 3, 4, 5, 6, 7);
        }
#pragma unroll
        for (int mi = 0; mi < 2; ++mi) {
            const char* ap = As + (wm * 32 + mi * 16 + m16) * BKB;
            intx4 lo = *(const intx4*)(ap + pc0);
            intx4 hi = *(const intx4*)(ap + pc1);
            intx8 af = __builtin_shufflevector(lo, hi, 0, 1, 2, 3, 4, 5, 6, 7);
#pragma unroll
            for (int ni = 0; ni < 4; ++ni)
                acc[mi][ni] = __builtin_amdgcn_mfma_scale_f32_16x16x128_f8f6f4(
                    af, bfr[ni], acc[mi][ni], 0, 0, 0, 127, 0, 127);
        }
    }
    __syncthreads();                 // all ds_reads of As/Bs done before Dt overwrite

    // ---- pass 1: d2 row-major (chunk-swizzled); scan rows of strip a ----
    // 16x16 C layout: col = lane&15, row = quad*4 + reg
#pragma unroll
    for (int mi = 0; mi < 2; ++mi) {
        const int il = wm * 32 + mi * 16 + quad * 4;
#pragma unroll
        for (int ni = 0; ni < 4; ++ni) {
            const int jl = wn * 64 + ni * 16 + m16;
            const float sj = sqc_s[jl];
#pragma unroll
            for (int r = 0; r < 4; ++r) {
                float d2 = fmaxf(sqr_s[il + r] + sj - 2.0f * acc[mi][ni][r], 1e-12f);
                const int rw7 = (il + r) & 7;
                Dt[(il + r) * DT_LD + ((((jl >> 3) ^ rw7) << 3) | (jl & 7))] = (_Float16)d2;
            }
        }
    }
    __syncthreads();

    const float NINF = -__builtin_inff();
    const float PINF =  __builtin_inff();
    float pos5[5] = {NINF, NINF, NINF, NINF, NINF};
    float neg5[5] = {PINF, PINF, PINF, PINF, PINF};
    scan_quarter_row(Dt, labcam_b, srow, squad, labcam_a[srow], pos5, neg5);
    emit_lists4(pos5, neg5, squad, posp, negp, (size_t)(r0 + srow), b);

    if (a != b) {
        __syncthreads();             // pass-1 scan reads done before Dt overwrite
        // ---- pass 2: d2 transposed (b64 packed, swizzled); scan rows of strip b ----
#pragma unroll
        for (int ni = 0; ni < 4; ++ni) {
            const int jl = wn * 64 + ni * 16 + m16;
            const float sj = sqc_s[jl];
            const int cw = jl & 7;
#pragma unroll
            for (int mi = 0; mi < 2; ++mi) {
                const int il = wm * 32 + mi * 16 + quad * 4;
                halfx4 h;
#pragma unroll
                for (int r = 0; r < 4; ++r)
                    h[r] = (_Float16)fmaxf(sqr_s[il + r] + sj - 2.0f * acc[mi][ni][r], 1e-12f);
                *(halfx4*)(Dt + jl * DT_LD + ((((il >> 3) ^ cw) << 3) | (il & 7))) = h;
            }
        }
        __syncthreads();
#pragma unroll
        for (int k = 0; k < 5; ++k) { pos5[k] = NINF; neg5[k] = PINF; }
        scan_quarter_row(Dt, labcam_a, srow, squad, labcam_b[srow], pos5, neg5);
        emit_lists4(pos5, neg5, squad, posp, negp, (size_t)(c0 + srow), a);
    }
}

// ---- kernel 3 (R5-exact): merge 64 fp16 d2-lists/row, 4 thr/row, 1024-thr blocks ----
__global__ __launch_bounds__(1024) void k_merge_sym(const _Float16* __restrict__ posp,
        const _Float16* __restrict__ negp, const int* __restrict__ epoch_p,
        float* __restrict__ out, float* __restrict__ wsum_p, float* __restrict__ wpsum_p) {
    const int t = threadIdx.x;
    const int rq = t & 3;                       // quarter of the row's 320 halves
    const int row = blockIdx.x * 256 + (t >> 2);
    const float NINF = -__builtin_inff(), PINF = __builtin_inff();
    float p5[5] = {NINF, NINF, NINF, NINF, NINF};
    float n5[5] = {PINF, PINF, PINF, PINF, PINF};
    const halfx8* pv8 = (const halfx8*)(posp + (size_t)row * (KL_SYM * 5) + rq * 80);
    const halfx8* nv8 = (const halfx8*)(negp + (size_t)row * (KL_SYM * 5) + rq * 80);
#pragma unroll
    for (int k = 0; k < 10; ++k) {
        halfx8 v = pv8[k];
#pragma unroll
        for (int e = 0; e < 8; ++e) { float f = (float)v[e]; if (f > p5[4]) ins_desc(p5, f); }
    }
#pragma unroll
    for (int k = 0; k < 10; ++k) {
        halfx8 v = nv8[k];
#pragma unroll
        for (int e = 0; e < 8; ++e) { float f = (float)v[e]; if (f < n5[4]) ins_asc(n5, f); }
    }
    // butterfly merge across the 4 lanes of this row (snapshot-then-insert)
#pragma unroll
    for (int o = 1; o <= 2; o <<= 1) {
        float tp[5], tn[5];
#pragma unroll
        for (int k = 0; k < 5; ++k) { tp[k] = __shfl_xor(p5[k], o); tn[k] = __shfl_xor(n5[k], o); }
#pragma unroll
        for (int k = 0; k < 5; ++k) {
            if (tp[k] > p5[4]) ins_desc(p5, tp[k]);
            if (tn[k] < n5[4]) ins_asc(n5, tn[k]);
        }
    }
    // d2 -> dist on the 5 survivors only
    float s = 0.f; int c = 0;
#pragma unroll
    for (int k = 0; k < 5; ++k) { bool fin = (p5[k] > NINF); s += fin ? sqrtf(p5[k]) : 0.f; c += fin ? 1 : 0; }
    float d_ap = (c > 0) ? s / (float)c : NINF;
    s = 0.f; c = 0;
#pragma unroll
    for (int k = 0; k < 5; ++k) { bool fin = (n5[k] < PINF); s += fin ? sqrtf(n5[k]) : 0.f; c += fin ? 1 : 0; }
    float d_an = (c > 0) ? s / (float)c : PINF;

    float w0 = 0.f, wp = 0.f;
    if (rq == 0) {
        out[1 + row] = d_ap;
        out[1 + NROW + row] = d_an;
        float diff = d_ap - d_an;
        w0 = 1.0f / (1.0f + expf(-2.0f * diff));         // sigmoid(ALPHA*(d_ap-d_an))
        float p;
        if (*epoch_p < 10) {
            p = fmaxf(diff, 0.0f) + log1pf(expf(-fabsf(diff)));  // stable softplus
        } else {
            p = fmaxf(diff + 0.3f, 0.0f);                // relu(d_ap - d_an + MARGIN)
        }
        wp = w0 * p;
    }
#pragma unroll
    for (int o = 32; o > 0; o >>= 1) { w0 += __shfl_down(w0, o); wp += __shfl_down(wp, o); }
    __shared__ float rw[16], rp[16];
    if ((t & 63) == 0) { rw[t >> 6] = w0; rp[t >> 6] = wp; }
    __syncthreads();
    if (t == 0) {
        float sw = 0.f, swp = 0.f;
#pragma unroll
        for (int i = 0; i < 16; ++i) { sw += rw[i]; swp += rp[i]; }
        wsum_p[blockIdx.x]  = sw;
        wpsum_p[blockIdx.x] = swp;
    }
}

// ---- kernel 4: finalize loss scalar ----
__global__ void k_finalize(const float* __restrict__ wsum_p, const float* __restrict__ wpsum_p,
                           float* __restrict__ out) {
    if (threadIdx.x == 0) {
        float sw = 0.f, swp = 0.f;
        for (int i = 0; i < 32; ++i) { sw += wsum_p[i]; swp += wpsum_p[i]; }
        float M = fmaxf(sw / (float)NROW, 1e-12f);
        out[0] = swp / ((float)NROW * M);
    }
}

extern "C" void kernel_launch(void* const* d_in, const int* in_sizes, int n_in,
                              void* d_out, int out_size, void* d_ws, size_t ws_size,
                              hipStream_t stream) {
    const float* feats  = (const float*)d_in[0];
    const int*   labels = (const int*)d_in[1];
    const int*   camids = (const int*)d_in[2];
    const int*   epoch  = (const int*)d_in[3];
    float* out = (float*)d_out;
    char* ws = (char*)d_ws;

    // workspace layout (~27.3 MB; ws proven >= 44 MB in R4-R10)
    unsigned char* xb = (unsigned char*)ws;                            // 16,777,216 B
    float* sq = (float*)(ws + 16777216);                               //     32,768 B
    const size_t HALF_LIST_BYTES = (size_t)NROW * KL_SYM * 5 * 2;      //  5,242,880 B
    _Float16* posp = (_Float16*)(ws + 16777216 + 32768);
    _Float16* negp = (_Float16*)(ws + 16777216 + 32768 + HALF_LIST_BYTES);
    float* wsum_p  = (float*)(ws + 16777216 + 32768 + 2 * HALF_LIST_BYTES);
    float* wpsum_p = wsum_p + 32;

    k_normalize<<<NROW, 256, 0, stream>>>(feats, xb, sq);
    k_gemm_sym<<<NTILE, 512, 0, stream>>>(xb, sq, labels, camids, posp, negp);
    k_merge_sym<<<NROW / 256, 1024, 0, stream>>>(posp, negp, epoch, out, wsum_p, wpsum_p);
    k_finalize<<<1, 64, 0, stream>>>(wsum_p, wpsum_p, out);
}

// Round 12
// 247.587 us; speedup vs baseline: 1.2559x; 1.1475x over previous
//
#include <hip/hip_runtime.h>
#include <hip/hip_bf16.h>
#include <stdint.h>

// ---- types ----
typedef float   floatx4  __attribute__((ext_vector_type(4)));
typedef int     intx4    __attribute__((ext_vector_type(4)));
typedef int     intx8    __attribute__((ext_vector_type(8)));
typedef _Float16 halfx8  __attribute__((ext_vector_type(8)));
typedef _Float16 halfx4  __attribute__((ext_vector_type(4)));
typedef unsigned short ushort8 __attribute__((ext_vector_type(8)));

#define NROW 8192
#define NDIM 2048        // elements = bytes (fp8)
#define BM 128
#define BKB 128          // bytes per row per K-stage = 128 fp8 = 8 x 16B chunks
#define NSTRIP 64                       // NROW/BM
#define NOFF (NSTRIP*(NSTRIP-1)/2)      // 2016 off-diagonal tiles (dispatched first)
#define NTILE (NSTRIP*(NSTRIP+1)/2)     // 2080 total tiles
#define DT_LD 136        // Dt row stride in halves (272 B; rows 16B-aligned)
#define KL_SYM 64        // one 5-list per row per other-strip
#define MERGE_BLOCKS 128 // k_merge_sym grid (was 32 -> only 32 CUs busy)

// insert v into descending-sorted a[5] (keeps 5 largest)
__device__ __forceinline__ void ins_desc(float (&a)[5], float v) {
#pragma unroll
    for (int k = 0; k < 5; ++k) { float hi = fmaxf(a[k], v); float lo = fminf(a[k], v); a[k] = hi; v = lo; }
}
// insert v into ascending-sorted a[5] (keeps 5 smallest)
__device__ __forceinline__ void ins_asc(float (&a)[5], float v) {
#pragma unroll
    for (int k = 0; k < 5; ++k) { float lo = fminf(a[k], v); float hi = fmaxf(a[k], v); a[k] = lo; v = hi; }
}

__device__ __forceinline__ void load_lds16(const void* g, void* l) {
    // async global->LDS, 16B/lane, dest = wave-uniform base + lane*16
    __builtin_amdgcn_global_load_lds((__attribute__((address_space(1))) void*)(void*)g,
                                     (__attribute__((address_space(3))) void*)l,
                                     16, 0, 0);
}

// ---- kernel 1: L2 normalize rows, write fp8-e4m3 matrix + sq ----
// fp8 verified numerically in R8/R9 (absmax 0.0078 == bf16 path).
__global__ __launch_bounds__(256) void k_normalize(const float* __restrict__ feats,
                                                   unsigned char* __restrict__ xb,
                                                   float* __restrict__ sq) {
    const int row = blockIdx.x;
    const int t = threadIdx.x;
    const float* f = feats + (size_t)row * NDIM + t * 8;
    float4 v0 = *(const float4*)(f);
    float4 v1 = *(const float4*)(f + 4);
    float ss = v0.x*v0.x + v0.y*v0.y + v0.z*v0.z + v0.w*v0.w
             + v1.x*v1.x + v1.y*v1.y + v1.z*v1.z + v1.w*v1.w;
#pragma unroll
    for (int o = 32; o > 0; o >>= 1) ss += __shfl_down(ss, o);
    __shared__ float red[4];
    __shared__ float s_inv;
    if ((t & 63) == 0) red[t >> 6] = ss;
    __syncthreads();
    if (t == 0) {
        float tot = red[0] + red[1] + red[2] + red[3];
        float m = fmaxf(sqrtf(tot), 1e-12f);
        float inv = 1.0f / m;
        sq[row] = tot * inv * inv;
        s_inv = inv;
    }
    __syncthreads();
    float inv = s_inv;
    // pack 8 normalized floats -> 8 fp8 e4m3 (HW cvt)
    int w0 = __builtin_amdgcn_cvt_pk_fp8_f32(v0.x * inv, v0.y * inv, 0, false);
    w0     = __builtin_amdgcn_cvt_pk_fp8_f32(v0.z * inv, v0.w * inv, w0, true);
    int w1 = __builtin_amdgcn_cvt_pk_fp8_f32(v1.x * inv, v1.y * inv, 0, false);
    w1     = __builtin_amdgcn_cvt_pk_fp8_f32(v1.z * inv, v1.w * inv, w1, true);
    int2 pk; pk.x = w0; pk.y = w1;
    *(int2*)(xb + (size_t)row * NDIM + t * 8) = pk;
}

// ---- scan helper (R9 + ushort labels): half-row scan over 64 cols in d2 domain.
// Labels packed as ushort (label<<4|cam, 12 bits) -> one 16B load per 8 cols
// (was 2x int4).  Dt chunk-swizzle unchanged (measured best, R5/R9).
__device__ __forceinline__ void scan_half_row(const _Float16* Dt_,
        const unsigned short* labcam_cols,
        int srow, int shalf, int pli, float (&pos5)[5], float (&neg5)[5]) {
    const int jb = shalf * 64;
    const int sw = srow & 7;
#pragma unroll
    for (int c8 = 0; c8 < 8; ++c8) {
        // physical chunk = logical chunk ^ (row&7); labels indexed logically
        halfx8 v = *(const halfx8*)(Dt_ + srow * DT_LD + ((shalf * 8 + (c8 ^ sw)) << 3));
        ushort8 lcv = *(const ushort8*)(labcam_cols + jb + c8 * 8);
#pragma unroll
        for (int e = 0; e < 8; ++e) {
            float d2 = (float)v[e];
            int x = pli ^ (int)lcv[e];
            bool same_label = (x & ~15) == 0;
            bool same_cam   = (x & 15) == 0;
            if (same_label) {
                // positive: same label, cross-cam (i==j auto-excluded: same cam)
                if (!same_cam && d2 > pos5[4]) ins_desc(pos5, d2);
            } else {
                // negative: diff label; same-cam boost dist/1.2 == d2/1.44 (monotone)
                float vn = same_cam ? d2 * (1.0f / 1.44f) : d2;
                if (vn < neg5[4]) ins_asc(neg5, vn);
            }
        }
    }
}

// merge the two half-row lists (adjacent lanes; snapshot-then-insert) and emit fp16
__device__ __forceinline__ void emit_lists(float (&pos5)[5], float (&neg5)[5], int shalf,
        _Float16* posp, _Float16* negp, size_t gi, int slot) {
    float tp[5], tn[5];
#pragma unroll
    for (int k = 0; k < 5; ++k) { tp[k] = __shfl_xor(pos5[k], 1); tn[k] = __shfl_xor(neg5[k], 1); }
#pragma unroll
    for (int k = 0; k < 5; ++k) {
        if (tp[k] > pos5[4]) ins_desc(pos5, tp[k]);
        if (tn[k] < neg5[4]) ins_asc(neg5, tn[k]);
    }
    if (shalf == 0) {
        _Float16* pp = posp + (gi * KL_SYM + slot) * 5;
        _Float16* np = negp + (gi * KL_SYM + slot) * 5;
#pragma unroll
        for (int k = 0; k < 5; ++k) { pp[k] = (_Float16)pos5[k]; np[k] = (_Float16)neg5[k]; }
    }
}

// ---- kernel 2 (sym): R9-exact structure (measured best: 148.5 us).
// One block per triangle tile (a,b), b<=a; diagonals last.  MX-fp8 K-loop,
// 4 waves x 64x64 wave-tile (4x4 MFMA accs; read:MFMA = 1.0 — R11's 32x64
// shape at 1.5 regressed), (256,3) cap (R10 lesson: acc counts against the
// unified-file cap; (256,4) spills).
__global__ __launch_bounds__(256, 3) void k_gemm_sym(
        const unsigned char* __restrict__ xb, const float* __restrict__ sq,
        const int* __restrict__ labels, const int* __restrict__ camids,
        _Float16* __restrict__ posp, _Float16* __restrict__ negp) {
    __shared__ __align__(16) char smem[BM * DT_LD * 2 + 4 * BM * 4];
    char* As = smem;                          // [0, 16384)
    char* Bs = smem + BM * BKB;               // [16384, 32768)
    _Float16* Dt = (_Float16*)smem;           // [0, 34816) aliases As/Bs
    float* sqr_s = (float*)(smem + BM * DT_LD * 2);
    float* sqc_s = sqr_s + BM;
    unsigned short* labcam_a = (unsigned short*)(sqc_s + BM);
    unsigned short* labcam_b = labcam_a + BM;

    const int tid = threadIdx.x;
    const int w = tid >> 6, lane = tid & 63;
    const int wm = w >> 1, wn = w & 1;

    // tile decode: off-diagonal pairs (b<a) first, diagonals last (cheap tail)
    int a, b;
    {
        int bx = blockIdx.x;
        if (bx < NOFF) {
            a = (int)((1.0f + sqrtf(8.0f * (float)bx + 1.0f)) * 0.5f);
            while (a * (a - 1) / 2 > bx) --a;
            while (a * (a + 1) / 2 <= bx) ++a;
            b = bx - a * (a - 1) / 2;
        } else {
            a = b = bx - NOFF;
        }
    }
    const int r0 = a * BM, c0 = b * BM;

    if (tid < BM) {
        int gi = r0 + tid;
        sqr_s[tid] = sq[gi];
        labcam_a[tid] = (unsigned short)((labels[gi] << 4) | camids[gi]);
    } else {
        int t2 = tid - BM;
        int gj = c0 + t2;
        sqc_s[t2] = sq[gj];
        labcam_b[t2] = (unsigned short)((labels[gj] << 4) | camids[gj]);
    }
    __syncthreads();

    const int srow = tid >> 1;       // scan: 2 threads per row
    const int shalf = tid & 1;

    const int lr = lane >> 3;                  // staging: row within 8-row chunk
    const int lc = ((lane & 7) ^ lr) * 16;     // staging: swizzled source chunk, bytes
    const int m16 = lane & 15;
    const int quad = lane >> 4;
    const int s7 = m16 & 7;                    // frag-read swizzle key (= row&7)
    const int pc0 = ((2 * quad) ^ s7) * 16;    // physical byte offset of logical chunk 2q
    const int pc1 = ((2 * quad + 1) ^ s7) * 16;

    floatx4 acc[4][4];
#pragma unroll
    for (int mi = 0; mi < 4; ++mi)
#pragma unroll
        for (int ni = 0; ni < 4; ++ni) {
            floatx4 z = {0.f, 0.f, 0.f, 0.f};
            acc[mi][ni] = z;
        }

    for (int kk = 0; kk < NDIM; kk += BKB) {   // 16 stages
        __syncthreads();             // previous iter's LDS consumers done
#pragma unroll
        for (int q = 0; q < 4; ++q) {
            const int ra = w * 32 + q * 8;    // wave-uniform 8-row chunk base
            load_lds16(xb + (size_t)(r0 + ra + lr) * NDIM + kk + lc, As + ra * BKB);
            load_lds16(xb + (size_t)(c0 + ra + lr) * NDIM + kk + lc, Bs + ra * BKB);
        }
        __syncthreads();             // drains vmcnt(0): data in LDS
        intx8 bfr[4];
#pragma unroll
        for (int ni = 0; ni < 4; ++ni) {
            const char* bp = Bs + (wn * 64 + ni * 16 + m16) * BKB;
            intx4 lo = *(const intx4*)(bp + pc0);
            intx4 hi = *(const intx4*)(bp + pc1);
            bfr[ni] = __builtin_shufflevector(lo, hi, 0, 1, 2, 3, 4, 5, 6, 7);
        }
#pragma unroll
        for (int mi = 0; mi < 4; ++mi) {
            const char* ap = As + (wm * 64 + mi * 16 + m16) * BKB;
            intx4 lo = *(const intx4*)(ap + pc0);
            intx4 hi = *(const intx4*)(ap + pc1);
            intx8 af = __builtin_shufflevector(lo, hi, 0, 1, 2, 3, 4, 5, 6, 7);
#pragma unroll
            for (int ni = 0; ni < 4; ++ni)
                acc[mi][ni] = __builtin_amdgcn_mfma_scale_f32_16x16x128_f8f6f4(
                    af, bfr[ni], acc[mi][ni], 0, 0, 0, 127, 0, 127);
        }
    }
    __syncthreads();                 // all ds_reads of As/Bs done before Dt overwrite

    // ---- pass 1: d2 row-major (chunk-swizzled); scan rows of strip a ----
    // 16x16 C layout: col = lane&15, row = quad*4 + reg
#pragma unroll
    for (int mi = 0; mi < 4; ++mi) {
        const int il = wm * 64 + mi * 16 + quad * 4;
#pragma unroll
        for (int ni = 0; ni < 4; ++ni) {
            const int jl = wn * 64 + ni * 16 + m16;
            const float sj = sqc_s[jl];
#pragma unroll
            for (int r = 0; r < 4; ++r) {
                float d2 = fmaxf(sqr_s[il + r] + sj - 2.0f * acc[mi][ni][r], 1e-12f);
                const int rw7 = (il + r) & 7;
                Dt[(il + r) * DT_LD + ((((jl >> 3) ^ rw7) << 3) | (jl & 7))] = (_Float16)d2;
            }
        }
    }
    __syncthreads();

    const float NINF = -__builtin_inff();
    const float PINF =  __builtin_inff();
    float pos5[5] = {NINF, NINF, NINF, NINF, NINF};
    float neg5[5] = {PINF, PINF, PINF, PINF, PINF};
    scan_half_row(Dt, labcam_b, srow, shalf, (int)labcam_a[srow], pos5, neg5);
    emit_lists(pos5, neg5, shalf, posp, negp, (size_t)(r0 + srow), b);

    if (a != b) {
        __syncthreads();             // pass-1 scan reads done before Dt overwrite
        // ---- pass 2: d2 transposed (b64 packed, swizzled); scan rows of strip b ----
#pragma unroll
        for (int ni = 0; ni < 4; ++ni) {
            const int jl = wn * 64 + ni * 16 + m16;
            const float sj = sqc_s[jl];
            const int cw = jl & 7;
#pragma unroll
            for (int mi = 0; mi < 4; ++mi) {
                const int il = wm * 64 + mi * 16 + quad * 4;
                halfx4 h;
#pragma unroll
                for (int r = 0; r < 4; ++r)
                    h[r] = (_Float16)fmaxf(sqr_s[il + r] + sj - 2.0f * acc[mi][ni][r], 1e-12f);
                *(halfx4*)(Dt + jl * DT_LD + ((((il >> 3) ^ cw) << 3) | (il & 7))) = h;
            }
        }
        __syncthreads();
#pragma unroll
        for (int k = 0; k < 5; ++k) { pos5[k] = NINF; neg5[k] = PINF; }
        scan_half_row(Dt, labcam_a, srow, shalf, (int)labcam_b[srow], pos5, neg5);
        emit_lists(pos5, neg5, shalf, posp, negp, (size_t)(c0 + srow), a);
    }
}

// ---- kernel 3: merge 64 fp16 d2-lists/row, 4 thr/row.  128 blocks x 256 thr
// (was 32 x 1024 -> only 32 of 256 CUs busy; latency-bound underutilization).
__global__ __launch_bounds__(256) void k_merge_sym(const _Float16* __restrict__ posp,
        const _Float16* __restrict__ negp, const int* __restrict__ epoch_p,
        float* __restrict__ out, float* __restrict__ wsum_p, float* __restrict__ wpsum_p) {
    const int t = threadIdx.x;
    const int rq = t & 3;                       // quarter of the row's 320 halves
    const int row = blockIdx.x * 64 + (t >> 2);
    const float NINF = -__builtin_inff(), PINF = __builtin_inff();
    float p5[5] = {NINF, NINF, NINF, NINF, NINF};
    float n5[5] = {PINF, PINF, PINF, PINF, PINF};
    const halfx8* pv8 = (const halfx8*)(posp + (size_t)row * (KL_SYM * 5) + rq * 80);
    const halfx8* nv8 = (const halfx8*)(negp + (size_t)row * (KL_SYM * 5) + rq * 80);
#pragma unroll
    for (int k = 0; k < 10; ++k) {
        halfx8 v = pv8[k];
#pragma unroll
        for (int e = 0; e < 8; ++e) { float f = (float)v[e]; if (f > p5[4]) ins_desc(p5, f); }
    }
#pragma unroll
    for (int k = 0; k < 10; ++k) {
        halfx8 v = nv8[k];
#pragma unroll
        for (int e = 0; e < 8; ++e) { float f = (float)v[e]; if (f < n5[4]) ins_asc(n5, f); }
    }
    // butterfly merge across the 4 lanes of this row (snapshot-then-insert)
#pragma unroll
    for (int o = 1; o <= 2; o <<= 1) {
        float tp[5], tn[5];
#pragma unroll
        for (int k = 0; k < 5; ++k) { tp[k] = __shfl_xor(p5[k], o); tn[k] = __shfl_xor(n5[k], o); }
#pragma unroll
        for (int k = 0; k < 5; ++k) {
            if (tp[k] > p5[4]) ins_desc(p5, tp[k]);
            if (tn[k] < n5[4]) ins_asc(n5, tn[k]);
        }
    }
    // d2 -> dist on the 5 survivors only
    float s = 0.f; int c = 0;
#pragma unroll
    for (int k = 0; k < 5; ++k) { bool fin = (p5[k] > NINF); s += fin ? sqrtf(p5[k]) : 0.f; c += fin ? 1 : 0; }
    float d_ap = (c > 0) ? s / (float)c : NINF;
    s = 0.f; c = 0;
#pragma unroll
    for (int k = 0; k < 5; ++k) { bool fin = (n5[k] < PINF); s += fin ? sqrtf(n5[k]) : 0.f; c += fin ? 1 : 0; }
    float d_an = (c > 0) ? s / (float)c : PINF;

    float w0 = 0.f, wp = 0.f;
    if (rq == 0) {
        out[1 + row] = d_ap;
        out[1 + NROW + row] = d_an;
        float diff = d_ap - d_an;
        w0 = 1.0f / (1.0f + expf(-2.0f * diff));         // sigmoid(ALPHA*(d_ap-d_an))
        float p;
        if (*epoch_p < 10) {
            p = fmaxf(diff, 0.0f) + log1pf(expf(-fabsf(diff)));  // stable softplus
        } else {
            p = fmaxf(diff + 0.3f, 0.0f);                // relu(d_ap - d_an + MARGIN)
        }
        wp = w0 * p;
    }
#pragma unroll
    for (int o = 32; o > 0; o >>= 1) { w0 += __shfl_down(w0, o); wp += __shfl_down(wp, o); }
    __shared__ float rw[4], rp[4];
    if ((t & 63) == 0) { rw[t >> 6] = w0; rp[t >> 6] = wp; }
    __syncthreads();
    if (t == 0) {
        wsum_p[blockIdx.x]  = rw[0] + rw[1] + rw[2] + rw[3];
        wpsum_p[blockIdx.x] = rp[0] + rp[1] + rp[2] + rp[3];
    }
}

// ---- kernel 4: finalize loss scalar ----
__global__ void k_finalize(const float* __restrict__ wsum_p, const float* __restrict__ wpsum_p,
                           float* __restrict__ out) {
    if (threadIdx.x == 0) {
        float sw = 0.f, swp = 0.f;
        for (int i = 0; i < MERGE_BLOCKS; ++i) { sw += wsum_p[i]; swp += wpsum_p[i]; }
        float M = fmaxf(sw / (float)NROW, 1e-12f);
        out[0] = swp / ((float)NROW * M);
    }
}

extern "C" void kernel_launch(void* const* d_in, const int* in_sizes, int n_in,
                              void* d_out, int out_size, void* d_ws, size_t ws_size,
                              hipStream_t stream) {
    const float* feats  = (const float*)d_in[0];
    const int*   labels = (const int*)d_in[1];
    const int*   camids = (const int*)d_in[2];
    const int*   epoch  = (const int*)d_in[3];
    float* out = (float*)d_out;
    char* ws = (char*)d_ws;

    // workspace layout (~27.3 MB; ws proven >= 44 MB in R4-R11)
    unsigned char* xb = (unsigned char*)ws;                            // 16,777,216 B
    float* sq = (float*)(ws + 16777216);                               //     32,768 B
    const size_t HALF_LIST_BYTES = (size_t)NROW * KL_SYM * 5 * 2;      //  5,242,880 B
    _Float16* posp = (_Float16*)(ws + 16777216 + 32768);
    _Float16* negp = (_Float16*)(ws + 16777216 + 32768 + HALF_LIST_BYTES);
    float* wsum_p  = (float*)(ws + 16777216 + 32768 + 2 * HALF_LIST_BYTES);
    float* wpsum_p = wsum_p + MERGE_BLOCKS;

    k_normalize<<<NROW, 256, 0, stream>>>(feats, xb, sq);
    k_gemm_sym<<<NTILE, 256, 0, stream>>>(xb, sq, labels, camids, posp, negp);
    k_merge_sym<<<MERGE_BLOCKS, 256, 0, stream>>>(posp, negp, epoch, out, wsum_p, wpsum_p);
    k_finalize<<<1, 64, 0, stream>>>(wsum_p, wpsum_p, out);
}